// Round 5
// baseline (113.021 us; speedup 1.0000x reference)
//
#include <hip/hip_runtime.h>
#include <stdint.h>

typedef __attribute__((ext_vector_type(8))) short bf16x8;
typedef __attribute__((ext_vector_type(4))) float f32x4;
typedef unsigned short u16;

constexpr int NN = 2048, NF = 256;

__device__ inline u16 f2bf(float f) {
  uint32_t u = __builtin_bit_cast(uint32_t, f);
  uint32_t r = (u + 0x7FFFu + ((u >> 16) & 1u)) >> 16;
  return (u16)r;
}
__device__ inline float bf2f(u16 h) {
  uint32_t u = ((uint32_t)h) << 16;
  return __builtin_bit_cast(float, u);
}

__device__ inline void gload_lds16(const void* g, void* l) {
  __builtin_amdgcn_global_load_lds(
      (const __attribute__((address_space(1))) uint32_t*)g,
      (__attribute__((address_space(3))) uint32_t*)l,
      16, 0, 0);
}

// ---- K1: d[row]=rsqrt(1+sum adj[row,:]); adjb=bf16(adj); tail blocks: Wconv
__global__ __launch_bounds__(256) void k_rowsum(const float* __restrict__ adj,
                                                u16* __restrict__ adjb,
                                                float* __restrict__ d,
                                                const float* __restrict__ W,
                                                u16* __restrict__ Wb) {
  if (blockIdx.x >= 16384) {  // W fp32 -> bf16 (64 blocks)
    int i = (blockIdx.x - 16384) * 256 + threadIdx.x;
    float4 v = ((const float4*)W)[i];
    ushort4 o;
    o.x = f2bf(v.x); o.y = f2bf(v.y); o.z = f2bf(v.z); o.w = f2bf(v.w);
    *(ushort4*)(Wb + (size_t)i * 4) = o;
    return;
  }
  int row = blockIdx.x;
  const float4* p = (const float4*)(adj + (size_t)row * NN);
  u16* ob = adjb + (size_t)row * NN;
  float s = 0.f;
#pragma unroll
  for (int c = 0; c < 2; ++c) {
    int idx = threadIdx.x + 256 * c;
    float4 v = p[idx];
    s += v.x + v.y + v.z + v.w;
    ushort4 o;
    o.x = f2bf(v.x); o.y = f2bf(v.y); o.z = f2bf(v.z); o.w = f2bf(v.w);
    *(ushort4*)(ob + (size_t)idx * 4) = o;
  }
#pragma unroll
  for (int off = 32; off > 0; off >>= 1) s += __shfl_down(s, off, 64);
  __shared__ float red[4];
  int lane = threadIdx.x & 63, w = threadIdx.x >> 6;
  if (lane == 0) red[w] = s;
  __syncthreads();
  if (threadIdx.x == 0) {
    float t = red[0] + red[1] + red[2] + red[3] + 1.0f;
    d[row] = 1.0f / sqrtf(t);
  }
}

// ---- K2: XpT[b,f,j] = bf16(d_j * X[b,j,f]) (plain transpose, no swizzle) ---
__global__ __launch_bounds__(256) void k_xprep(const float* __restrict__ X,
                                               const float* __restrict__ d,
                                               u16* __restrict__ XpT) {
  int jt = blockIdx.x, ft = blockIdx.y, b = blockIdx.z;
  int j0 = jt * 64, f0 = ft * 64;
  __shared__ u16 T[64][66];
  int t = threadIdx.x;
#pragma unroll
  for (int s = 0; s < 4; ++s) {
    int q = s * 256 + t;
    int r = q >> 4, c4 = q & 15;
    int j = j0 + r;
    float dv = d[b * NN + j];
    float4 v = *(const float4*)(X + ((size_t)(b * NN + j)) * NF + f0 + c4 * 4);
    T[r][c4 * 4 + 0] = f2bf(v.x * dv);
    T[r][c4 * 4 + 1] = f2bf(v.y * dv);
    T[r][c4 * 4 + 2] = f2bf(v.z * dv);
    T[r][c4 * 4 + 3] = f2bf(v.w * dv);
  }
  __syncthreads();
#pragma unroll
  for (int s = 0; s < 4; ++s) {
    int q = s * 256 + t;
    int fr = q >> 4, c4 = q & 15;
    ushort4 o;
    o.x = T[c4 * 4 + 0][fr]; o.y = T[c4 * 4 + 1][fr];
    o.z = T[c4 * 4 + 2][fr]; o.w = T[c4 * 4 + 3][fr];
    *(ushort4*)(XpT + ((size_t)(b * NF + f0 + fr)) * NN + j0 + c4 * 4) = o;
  }
}

// ---- Fused: H = d_i*(adjb@Xp + Xp_i) ; out = relu(H@W^T + bias) ------------
// BM=32, BN=256, BK=32, 256 thr (4 waves 1x4), 512 blocks = 2/CU.
// B-frags: global(L2)->regs, depth-2.  A: 4-buf LDS glds, counted vmcnt+s_barrier.
#define FUSED_STEP(K, BR, VMC, DO_ISSUE)                                       \
  {                                                                            \
    asm volatile("s_waitcnt vmcnt(" VMC ")" ::: "memory");                     \
    __builtin_amdgcn_sched_barrier(0);                                         \
    __builtin_amdgcn_s_barrier();                                              \
    if (DO_ISSUE) {                                                            \
      if (lane < 32)                                                           \
        gload_lds16(a_src + (size_t)((K) + 2) * 32,                            \
                    smem + ((((K) + 2) & 3) << 11) + (w << 9));                \
    }                                                                          \
    __builtin_amdgcn_sched_barrier(0);                                         \
    char* Ab = smem + (((K) & 3) << 11);                                       \
    bf16x8 af0 = *(const bf16x8*)(Ab + aoff0);                                 \
    bf16x8 af1 = *(const bf16x8*)(Ab + aoff1);                                 \
    asm volatile("s_waitcnt lgkmcnt(0)" ::: "memory");                         \
    __builtin_amdgcn_sched_barrier(0);                                         \
    __builtin_amdgcn_s_setprio(1);                                             \
    acc[0][0] = __builtin_amdgcn_mfma_f32_16x16x32_bf16(af0, BR[0], acc[0][0], 0, 0, 0); \
    acc[0][1] = __builtin_amdgcn_mfma_f32_16x16x32_bf16(af0, BR[1], acc[0][1], 0, 0, 0); \
    acc[0][2] = __builtin_amdgcn_mfma_f32_16x16x32_bf16(af0, BR[2], acc[0][2], 0, 0, 0); \
    acc[0][3] = __builtin_amdgcn_mfma_f32_16x16x32_bf16(af0, BR[3], acc[0][3], 0, 0, 0); \
    acc[1][0] = __builtin_amdgcn_mfma_f32_16x16x32_bf16(af1, BR[0], acc[1][0], 0, 0, 0); \
    acc[1][1] = __builtin_amdgcn_mfma_f32_16x16x32_bf16(af1, BR[1], acc[1][1], 0, 0, 0); \
    acc[1][2] = __builtin_amdgcn_mfma_f32_16x16x32_bf16(af1, BR[2], acc[1][2], 0, 0, 0); \
    acc[1][3] = __builtin_amdgcn_mfma_f32_16x16x32_bf16(af1, BR[3], acc[1][3], 0, 0, 0); \
    __builtin_amdgcn_s_setprio(0);                                             \
    __builtin_amdgcn_sched_barrier(0);                                         \
    if (DO_ISSUE) {                                                            \
      BR[0] = *(const bf16x8*)(bp0 + (size_t)((K) + 2) * 32);                  \
      BR[1] = *(const bf16x8*)(bp1 + (size_t)((K) + 2) * 32);                  \
      BR[2] = *(const bf16x8*)(bp2 + (size_t)((K) + 2) * 32);                  \
      BR[3] = *(const bf16x8*)(bp3 + (size_t)((K) + 2) * 32);                  \
    }                                                                          \
    __builtin_amdgcn_sched_barrier(0);                                         \
  }

__global__ __launch_bounds__(256, 2) void k_fused(
    const u16* __restrict__ adjb, const u16* __restrict__ XpT,
    const float* __restrict__ dsc, const u16* __restrict__ Wb,
    const float* __restrict__ bias, float* __restrict__ out) {
  int flat = blockIdx.x;
  int b = flat & 7, mt = flat >> 3;  // batch->XCD affinity
  int i0 = mt * 32;

  __shared__ __align__(16) char smem[17408];  // bufA 4x2KB | Hs 16.9KB (alias)
  u16* Hs = (u16*)smem;

  int t = threadIdx.x;
  int lane = t & 63, w = t >> 6;
  int l15 = lane & 15, l4 = lane >> 4;
  int wc = w;

  const u16* adjbb = adjb + ((size_t)b * NN + i0) * NN;
  const u16* XpTb = XpT + (size_t)b * NF * NN;

  // A glds source map (lanes 0..31 per wave): row rl, chunk pre-swizzled
  int rl = (w << 3) + ((lane & 31) >> 2);
  int asrc_off = ((lane & 3) ^ ((rl >> 1) & 3)) * 8;
  const u16* a_src = adjbb + (size_t)rl * NN + asrc_off;

  // A frag LDS byte offsets (within one 2KB buffer); rows r and r+16 same swz
  int aoff0 = l15 * 64 + ((l4 ^ ((l15 >> 1) & 3)) << 4);
  int aoff1 = aoff0 + 1024;

  // B frag base pointers (natural layout, 16 rows x 64B lines per frag)
  const u16* bp0 = XpTb + (size_t)(wc * 64 + l15) * NN + l4 * 8;
  const u16* bp1 = bp0 + (size_t)16 * NN;
  const u16* bp2 = bp0 + (size_t)32 * NN;
  const u16* bp3 = bp0 + (size_t)48 * NN;

  f32x4 acc[2][4] = {};
  bf16x8 brA[4], brB[4];

  // ---- prologue: A0, B0, A1, B1 (issue order pinned) ----
  if (lane < 32) gload_lds16(a_src, smem + (w << 9));
  __builtin_amdgcn_sched_barrier(0);
  brA[0] = *(const bf16x8*)(bp0);
  brA[1] = *(const bf16x8*)(bp1);
  brA[2] = *(const bf16x8*)(bp2);
  brA[3] = *(const bf16x8*)(bp3);
  __builtin_amdgcn_sched_barrier(0);
  if (lane < 32) gload_lds16(a_src + 32, smem + 2048 + (w << 9));
  __builtin_amdgcn_sched_barrier(0);
  brB[0] = *(const bf16x8*)(bp0 + 32);
  brB[1] = *(const bf16x8*)(bp1 + 32);
  brB[2] = *(const bf16x8*)(bp2 + 32);
  brB[3] = *(const bf16x8*)(bp3 + 32);
  __builtin_amdgcn_sched_barrier(0);

  // ---- main loop: steps 0..61 (hot), 62..63 (peeled, no issue) ----
  for (int k2 = 0; k2 < 62; k2 += 2) {
    FUSED_STEP(k2, brA, "9", true);
    FUSED_STEP(k2 + 1, brB, "9", true);
  }
  FUSED_STEP(62, brA, "9", false);
  FUSED_STEP(63, brB, "4", false);

  __syncthreads();  // all frag reads done before Hs aliases bufA

  // ---- epilogue 1: H tile -> LDS bf16 [32][264]; +I term from XpT (L2) ----
  const float* db = dsc + b * NN;
#pragma unroll
  for (int mi = 0; mi < 2; ++mi) {
#pragma unroll
    for (int ni = 0; ni < 4; ++ni) {
      int f = wc * 64 + ni * 16 + l15;
      ushort4 xv = *(const ushort4*)(XpTb + (size_t)f * NN + i0 + mi * 16 + l4 * 4);
#pragma unroll
      for (int qq = 0; qq < 4; ++qq) {
        int il = mi * 16 + l4 * 4 + qq;
        float dv = db[i0 + il];
        float xpv = bf2f(((const u16*)&xv)[qq]);
        float hv = dv * (acc[mi][ni][qq] + xpv);
        Hs[il * 264 + f] = f2bf(hv);
      }
    }
  }
  __syncthreads();

  // ---- epilogue 2: out = relu(H @ W^T + bias), W frags from L2 ----
  f32x4 acc2[2][4] = {};
#pragma unroll
  for (int kk = 0; kk < 256; kk += 32) {
    bf16x8 a2[2], b2[4];
#pragma unroll
    for (int mi = 0; mi < 2; ++mi) {
      int r = mi * 16 + l15;
      a2[mi] = *(const bf16x8*)&Hs[r * 264 + kk + l4 * 8];
    }
#pragma unroll
    for (int ni = 0; ni < 4; ++ni) {
      int o = wc * 64 + ni * 16 + l15;
      b2[ni] = *(const bf16x8*)&Wb[(size_t)o * 256 + kk + l4 * 8];
    }
#pragma unroll
    for (int mi = 0; mi < 2; ++mi)
#pragma unroll
      for (int ni = 0; ni < 4; ++ni)
        acc2[mi][ni] = __builtin_amdgcn_mfma_f32_16x16x32_bf16(a2[mi], b2[ni],
                                                               acc2[mi][ni], 0, 0, 0);
  }

  float* outb = out + ((size_t)b * NN + i0) * NF;
#pragma unroll
  for (int mi = 0; mi < 2; ++mi) {
#pragma unroll
    for (int qq = 0; qq < 4; ++qq) {
      int il = mi * 16 + l4 * 4 + qq;
#pragma unroll
      for (int ni = 0; ni < 4; ++ni) {
        int o = wc * 64 + ni * 16 + l15;
        float v = acc2[mi][ni][qq] + bias[o];
        outb[(size_t)il * NF + o] = fmaxf(v, 0.f);
      }
    }
  }
}

extern "C" void kernel_launch(void* const* d_in, const int* in_sizes, int n_in,
                              void* d_out, int out_size, void* d_ws, size_t ws_size,
                              hipStream_t stream) {
  const float* X    = (const float*)d_in[0];
  const float* adj  = (const float*)d_in[1];
  const float* W    = (const float*)d_in[2];
  const float* bias = (const float*)d_in[3];
  float* out = (float*)d_out;

  char* ws = (char*)d_ws;
  float* dsc  = (float*)(ws);                          // 64 KB
  u16*   Wb   = (u16*)(ws + 65536);                    // 128 KB
  u16*   XpT  = (u16*)(ws + 262144);                   // 8 MB
  u16*   adjb = (u16*)(ws + 262144 + 8388608);         // 64 MB

  k_rowsum<<<dim3(16448), dim3(256), 0, stream>>>(adj, adjb, dsc, W, Wb);
  k_xprep<<<dim3(32, 4, 8), dim3(256), 0, stream>>>(X, dsc, XpT);
  k_fused<<<dim3(512), dim3(256), 0, stream>>>(adjb, XpT, dsc, Wb, bias, out);
}

// Round 6
// 85.124 us; speedup vs baseline: 1.3277x; 1.3277x over previous
//
#include <hip/hip_runtime.h>
#include <stdint.h>

typedef __attribute__((ext_vector_type(8))) short bf16x8;
typedef __attribute__((ext_vector_type(4))) float f32x4;
typedef unsigned short u16;

constexpr int NN = 2048, NF = 256;

__device__ inline u16 f2bf(float f) {
  uint32_t u = __builtin_bit_cast(uint32_t, f);
  uint32_t r = (u + 0x7FFFu + ((u >> 16) & 1u)) >> 16;
  return (u16)r;
}
__device__ inline float bf2f(u16 h) {
  uint32_t u = ((uint32_t)h) << 16;
  return __builtin_bit_cast(float, u);
}

__device__ inline void gload_lds16(const void* g, void* l) {
  __builtin_amdgcn_global_load_lds(
      (const __attribute__((address_space(1))) uint32_t*)g,
      (__attribute__((address_space(3))) uint32_t*)l,
      16, 0, 0);
}

// ---- K1: d[row]=rsqrt(1+sum adj[row,:]); adjb=bf16(adj); tail blocks: Wconv
__global__ __launch_bounds__(256) void k_rowsum(const float* __restrict__ adj,
                                                u16* __restrict__ adjb,
                                                float* __restrict__ d,
                                                const float* __restrict__ W,
                                                u16* __restrict__ Wb) {
  if (blockIdx.x >= 16384) {  // W fp32 -> bf16 (64 blocks)
    int i = (blockIdx.x - 16384) * 256 + threadIdx.x;
    float4 v = ((const float4*)W)[i];
    ushort4 o;
    o.x = f2bf(v.x); o.y = f2bf(v.y); o.z = f2bf(v.z); o.w = f2bf(v.w);
    *(ushort4*)(Wb + (size_t)i * 4) = o;
    return;
  }
  int row = blockIdx.x;
  const float4* p = (const float4*)(adj + (size_t)row * NN);
  u16* ob = adjb + (size_t)row * NN;
  float s = 0.f;
#pragma unroll
  for (int c = 0; c < 2; ++c) {
    int idx = threadIdx.x + 256 * c;
    float4 v = p[idx];
    s += v.x + v.y + v.z + v.w;
    ushort4 o;
    o.x = f2bf(v.x); o.y = f2bf(v.y); o.z = f2bf(v.z); o.w = f2bf(v.w);
    *(ushort4*)(ob + (size_t)idx * 4) = o;
  }
#pragma unroll
  for (int off = 32; off > 0; off >>= 1) s += __shfl_down(s, off, 64);
  __shared__ float red[4];
  int lane = threadIdx.x & 63, w = threadIdx.x >> 6;
  if (lane == 0) red[w] = s;
  __syncthreads();
  if (threadIdx.x == 0) {
    float t = red[0] + red[1] + red[2] + red[3] + 1.0f;
    d[row] = 1.0f / sqrtf(t);
  }
}

// ---- K2: XpT[b,f,j'] = bf16(d_j*X[b,j,f]), j' = j ^ (((f>>1)&3)<<3) --------
__global__ __launch_bounds__(256) void k_xprep(const float* __restrict__ X,
                                               const float* __restrict__ d,
                                               u16* __restrict__ XpT) {
  int jt = blockIdx.x, ft = blockIdx.y, b = blockIdx.z;
  int j0 = jt * 64, f0 = ft * 64;
  __shared__ u16 T[64][66];
  int t = threadIdx.x;
#pragma unroll
  for (int s = 0; s < 4; ++s) {
    int q = s * 256 + t;
    int r = q >> 4, c4 = q & 15;
    int j = j0 + r;
    float dv = d[b * NN + j];
    float4 v = *(const float4*)(X + ((size_t)(b * NN + j)) * NF + f0 + c4 * 4);
    T[r][c4 * 4 + 0] = f2bf(v.x * dv);
    T[r][c4 * 4 + 1] = f2bf(v.y * dv);
    T[r][c4 * 4 + 2] = f2bf(v.z * dv);
    T[r][c4 * 4 + 3] = f2bf(v.w * dv);
  }
  __syncthreads();
#pragma unroll
  for (int s = 0; s < 4; ++s) {
    int q = s * 256 + t;
    int fr = q >> 4, c4 = q & 15;
    int f = f0 + fr;
    int swz = (f >> 1) & 3;
    int joff = (c4 * 4) ^ (swz << 3);
    ushort4 o;
    o.x = T[c4 * 4 + 0][fr]; o.y = T[c4 * 4 + 1][fr];
    o.z = T[c4 * 4 + 2][fr]; o.w = T[c4 * 4 + 3][fr];
    *(ushort4*)(XpT + ((size_t)(b * NF + f)) * NN + j0 + joff) = o;
  }
}

// ---- Fused: H = d_i*(adjb@Xp + Xp_i) ; out = relu(H@W^T + bias) ------------
// BM=32, BN=256, BK=32, 256 thr (4 waves 1x4), 512 blocks = 2/CU.
// All staging via gload_lds; depth-2 prefetch; counted vmcnt(9); raw s_barrier.
// A: 4KB granules (2 K-steps) triple-buffered @ smem[0..12K).
// B: 16KB per step, quad-buffered @ smem[12K..76K).
#define BBASE 12288

#define FUSED_STEP(K, AW, AR, BW, BRI, VMC, IA, IB)                            \
  {                                                                            \
    if (IA) {                                                                  \
      gload_lds16(a_src + (size_t)((K) + 2) * 32,                              \
                  smem + ((AW) << 12) + (w << 10));                            \
    }                                                                          \
    if (IB) {                                                                  \
      _Pragma("unroll")                                                        \
      for (int c = 0; c < 4; ++c) {                                            \
        int q = c * 256 + t;                                                   \
        gload_lds16(XpTb + (size_t)(q >> 2) * NN + ((K) + 2) * 32 + (q & 3) * 8, \
                    smem + BBASE + ((BW) << 14) + (c * 256 + w * 64) * 16);    \
      }                                                                        \
    }                                                                          \
    __builtin_amdgcn_sched_barrier(0);                                         \
    asm volatile("s_waitcnt vmcnt(" VMC ")" ::: "memory");                     \
    __builtin_amdgcn_sched_barrier(0);                                         \
    __builtin_amdgcn_s_barrier();                                              \
    __builtin_amdgcn_sched_barrier(0);                                         \
    const char* Ab = smem + ((AR) << 12) + (((K) & 1) << 11);                  \
    const char* Bb = smem + BBASE + ((BRI) << 14);                             \
    bf16x8 af0 = *(const bf16x8*)(Ab + aoff0);                                 \
    bf16x8 af1 = *(const bf16x8*)(Ab + aoff0 + 1024);                          \
    bf16x8 b0 = *(const bf16x8*)(Bb + boff0);                                  \
    bf16x8 b1 = *(const bf16x8*)(Bb + boff0 + 1024);                           \
    bf16x8 b2 = *(const bf16x8*)(Bb + boff0 + 2048);                           \
    bf16x8 b3 = *(const bf16x8*)(Bb + boff0 + 3072);                           \
    asm volatile("s_waitcnt lgkmcnt(0)" ::: "memory");                         \
    __builtin_amdgcn_sched_barrier(0);                                         \
    __builtin_amdgcn_s_setprio(1);                                             \
    acc[0][0] = __builtin_amdgcn_mfma_f32_16x16x32_bf16(af0, b0, acc[0][0], 0, 0, 0); \
    acc[0][1] = __builtin_amdgcn_mfma_f32_16x16x32_bf16(af0, b1, acc[0][1], 0, 0, 0); \
    acc[0][2] = __builtin_amdgcn_mfma_f32_16x16x32_bf16(af0, b2, acc[0][2], 0, 0, 0); \
    acc[0][3] = __builtin_amdgcn_mfma_f32_16x16x32_bf16(af0, b3, acc[0][3], 0, 0, 0); \
    acc[1][0] = __builtin_amdgcn_mfma_f32_16x16x32_bf16(af1, b0, acc[1][0], 0, 0, 0); \
    acc[1][1] = __builtin_amdgcn_mfma_f32_16x16x32_bf16(af1, b1, acc[1][1], 0, 0, 0); \
    acc[1][2] = __builtin_amdgcn_mfma_f32_16x16x32_bf16(af1, b2, acc[1][2], 0, 0, 0); \
    acc[1][3] = __builtin_amdgcn_mfma_f32_16x16x32_bf16(af1, b3, acc[1][3], 0, 0, 0); \
    __builtin_amdgcn_s_setprio(0);                                             \
    __builtin_amdgcn_sched_barrier(0);                                         \
  }

__global__ __launch_bounds__(256, 2) void k_fused(
    const u16* __restrict__ adjb, const u16* __restrict__ XpT,
    const float* __restrict__ dsc, const u16* __restrict__ Wb,
    const float* __restrict__ bias, float* __restrict__ out) {
  int flat = blockIdx.x;
  int b = flat & 7, mt = flat >> 3;  // batch->XCD affinity
  int i0 = mt * 32;

  __shared__ __align__(16) char smem[77824];  // A 3x4K | B 4x16K ; Hs aliases
  u16* Hs = (u16*)smem;

  int t = threadIdx.x;
  int lane = t & 63, w = t >> 6;
  int l15 = lane & 15, l4 = lane >> 4;
  int wc = w;

  const u16* adjbb = adjb + ((size_t)b * NN + i0) * NN;
  const u16* XpTb = XpT + (size_t)b * NF * NN;

  // A staging: thread t -> sub s=t>>7 (k-step within granule), row r, chunk c
  int as_ = t >> 7, ar_ = (t >> 2) & 31, ac_ = t & 3;
  const u16* a_src = adjbb + (size_t)ar_ * NN + as_ * 32 +
                     ((ac_ ^ ((ar_ >> 1) & 3)) << 3);

  // frag read byte offsets (within one 2KB A sub-tile / 16KB B tile)
  int aoff0 = l15 * 64 + ((l4 ^ ((l15 >> 1) & 3)) << 4);
  int n0 = wc * 64 + l15;
  int boff0 = n0 * 64 + ((l4 ^ ((n0 >> 1) & 3)) << 4);

  f32x4 acc[2][4] = {};

  // ---- prologue: A granule0 -> Abuf0; B(0) -> Bbuf0; B(1) -> Bbuf1 ----
  gload_lds16(a_src, smem + (w << 10));
#pragma unroll
  for (int c = 0; c < 4; ++c) {
    int q = c * 256 + t;
    gload_lds16(XpTb + (size_t)(q >> 2) * NN + (q & 3) * 8,
                smem + BBASE + (c * 256 + w * 64) * 16);
  }
#pragma unroll
  for (int c = 0; c < 4; ++c) {
    int q = c * 256 + t;
    gload_lds16(XpTb + (size_t)(q >> 2) * NN + 32 + (q & 3) * 8,
                smem + BBASE + 16384 + (c * 256 + w * 64) * 16);
  }
  __builtin_amdgcn_sched_barrier(0);

  // ---- main loop: 12-step body (A mod-3, B mod-4 literal indices) ----
  for (int kb = 0; kb < 60; kb += 12) {
    FUSED_STEP(kb + 0, 1, 0, 2, 0, "9", 1, 1)
    FUSED_STEP(kb + 1, 0, 0, 3, 1, "9", 0, 1)
    FUSED_STEP(kb + 2, 2, 1, 0, 2, "9", 1, 1)
    FUSED_STEP(kb + 3, 0, 1, 1, 3, "9", 0, 1)
    FUSED_STEP(kb + 4, 0, 2, 2, 0, "9", 1, 1)
    FUSED_STEP(kb + 5, 0, 2, 3, 1, "9", 0, 1)
    FUSED_STEP(kb + 6, 1, 0, 0, 2, "9", 1, 1)
    FUSED_STEP(kb + 7, 0, 0, 1, 3, "9", 0, 1)
    FUSED_STEP(kb + 8, 2, 1, 2, 0, "9", 1, 1)
    FUSED_STEP(kb + 9, 0, 1, 3, 1, "9", 0, 1)
    FUSED_STEP(kb + 10, 0, 2, 0, 2, "9", 1, 1)
    FUSED_STEP(kb + 11, 0, 2, 1, 3, "9", 0, 1)
  }
  // ---- peeled tail: steps 60..63 ----
  FUSED_STEP(60, 1, 0, 2, 0, "9", 1, 1)
  FUSED_STEP(61, 0, 0, 3, 1, "9", 0, 1)
  FUSED_STEP(62, 0, 1, 0, 2, "4", 0, 0)
  FUSED_STEP(63, 0, 1, 0, 3, "0", 0, 0)

  __syncthreads();  // full drain before Hs aliases the staging buffers

  // ---- epilogue 1: H tile -> LDS bf16 [32][264]; +I term from XpT (L2) ----
  const float* db = dsc + b * NN;
#pragma unroll
  for (int mi = 0; mi < 2; ++mi) {
#pragma unroll
    for (int ni = 0; ni < 4; ++ni) {
      int f = wc * 64 + ni * 16 + l15;
      int swz8 = ((f >> 1) & 3) << 3;
      ushort4 xv = *(const ushort4*)(XpTb + (size_t)f * NN + i0 +
                                     ((mi * 16 + l4 * 4) ^ swz8));
#pragma unroll
      for (int qq = 0; qq < 4; ++qq) {
        int il = mi * 16 + l4 * 4 + qq;
        float dv = db[i0 + il];
        float xpv = bf2f(((const u16*)&xv)[qq]);
        float hv = dv * (acc[mi][ni][qq] + xpv);
        Hs[il * 264 + f] = f2bf(hv);
      }
    }
  }
  __syncthreads();

  // ---- epilogue 2: out = relu(H @ W^T + bias), W frags from L2 ----
  f32x4 acc2[2][4] = {};
#pragma unroll
  for (int kk = 0; kk < 256; kk += 32) {
    bf16x8 a2[2], b2[4];
#pragma unroll
    for (int mi = 0; mi < 2; ++mi) {
      int r = mi * 16 + l15;
      a2[mi] = *(const bf16x8*)&Hs[r * 264 + kk + l4 * 8];
    }
#pragma unroll
    for (int ni = 0; ni < 4; ++ni) {
      int o = wc * 64 + ni * 16 + l15;
      b2[ni] = *(const bf16x8*)&Wb[(size_t)o * 256 + kk + l4 * 8];
    }
#pragma unroll
    for (int mi = 0; mi < 2; ++mi)
#pragma unroll
      for (int ni = 0; ni < 4; ++ni)
        acc2[mi][ni] = __builtin_amdgcn_mfma_f32_16x16x32_bf16(a2[mi], b2[ni],
                                                               acc2[mi][ni], 0, 0, 0);
  }

  float* outb = out + ((size_t)b * NN + i0) * NF;
#pragma unroll
  for (int mi = 0; mi < 2; ++mi) {
#pragma unroll
    for (int qq = 0; qq < 4; ++qq) {
      int il = mi * 16 + l4 * 4 + qq;
#pragma unroll
      for (int ni = 0; ni < 4; ++ni) {
        int o = wc * 64 + ni * 16 + l15;
        float v = acc2[mi][ni][qq] + bias[o];
        outb[(size_t)il * NF + o] = fmaxf(v, 0.f);
      }
    }
  }
}

extern "C" void kernel_launch(void* const* d_in, const int* in_sizes, int n_in,
                              void* d_out, int out_size, void* d_ws, size_t ws_size,
                              hipStream_t stream) {
  const float* X    = (const float*)d_in[0];
  const float* adj  = (const float*)d_in[1];
  const float* W    = (const float*)d_in[2];
  const float* bias = (const float*)d_in[3];
  float* out = (float*)d_out;

  char* ws = (char*)d_ws;
  float* dsc  = (float*)(ws);                          // 64 KB
  u16*   Wb   = (u16*)(ws + 65536);                    // 128 KB
  u16*   XpT  = (u16*)(ws + 262144);                   // 8 MB
  u16*   adjb = (u16*)(ws + 262144 + 8388608);         // 64 MB

  k_rowsum<<<dim3(16448), dim3(256), 0, stream>>>(adj, adjb, dsc, W, Wb);
  k_xprep<<<dim3(32, 4, 8), dim3(256), 0, stream>>>(X, dsc, XpT);
  k_fused<<<dim3(512), dim3(256), 0, stream>>>(adjb, XpT, dsc, Wb, bias, out);
}

// Round 7
// 75.681 us; speedup vs baseline: 1.4934x; 1.1248x over previous
//
#include <hip/hip_runtime.h>
#include <stdint.h>

typedef __attribute__((ext_vector_type(8))) short bf16x8;
typedef __attribute__((ext_vector_type(4))) float f32x4;
typedef unsigned short u16;

constexpr int NN = 2048, NF = 256;

__device__ inline u16 f2bf(float f) {
  uint32_t u = __builtin_bit_cast(uint32_t, f);
  uint32_t r = (u + 0x7FFFu + ((u >> 16) & 1u)) >> 16;
  return (u16)r;
}
__device__ inline float bf2f(u16 h) {
  uint32_t u = ((uint32_t)h) << 16;
  return __builtin_bit_cast(float, u);
}

__device__ inline void gload_lds16(const void* g, void* l) {
  __builtin_amdgcn_global_load_lds(
      (const __attribute__((address_space(1))) uint32_t*)g,
      (__attribute__((address_space(3))) uint32_t*)l,
      16, 0, 0);
}

// ---- K1: d[row]=rsqrt(1+sum adj[row,:]); adjb=bf16(adj); tail blocks: Wconv
__global__ __launch_bounds__(256) void k_rowsum(const float* __restrict__ adj,
                                                u16* __restrict__ adjb,
                                                float* __restrict__ d,
                                                const float* __restrict__ W,
                                                u16* __restrict__ Wb) {
  if (blockIdx.x >= 16384) {  // W fp32 -> bf16 (64 blocks)
    int i = (blockIdx.x - 16384) * 256 + threadIdx.x;
    float4 v = ((const float4*)W)[i];
    ushort4 o;
    o.x = f2bf(v.x); o.y = f2bf(v.y); o.z = f2bf(v.z); o.w = f2bf(v.w);
    *(ushort4*)(Wb + (size_t)i * 4) = o;
    return;
  }
  int row = blockIdx.x;
  const float4* p = (const float4*)(adj + (size_t)row * NN);
  u16* ob = adjb + (size_t)row * NN;
  float s = 0.f;
#pragma unroll
  for (int c = 0; c < 2; ++c) {
    int idx = threadIdx.x + 256 * c;
    float4 v = p[idx];
    s += v.x + v.y + v.z + v.w;
    ushort4 o;
    o.x = f2bf(v.x); o.y = f2bf(v.y); o.z = f2bf(v.z); o.w = f2bf(v.w);
    *(ushort4*)(ob + (size_t)idx * 4) = o;
  }
#pragma unroll
  for (int off = 32; off > 0; off >>= 1) s += __shfl_down(s, off, 64);
  __shared__ float red[4];
  int lane = threadIdx.x & 63, w = threadIdx.x >> 6;
  if (lane == 0) red[w] = s;
  __syncthreads();
  if (threadIdx.x == 0) {
    float t = red[0] + red[1] + red[2] + red[3] + 1.0f;
    d[row] = 1.0f / sqrtf(t);
  }
}

// ---- K2: XpT[b,f,j] = bf16(d_j * X[b,j,f])  (plain transpose) --------------
__global__ __launch_bounds__(256) void k_xprep(const float* __restrict__ X,
                                               const float* __restrict__ d,
                                               u16* __restrict__ XpT) {
  int jt = blockIdx.x, ft = blockIdx.y, b = blockIdx.z;
  int j0 = jt * 64, f0 = ft * 64;
  __shared__ u16 T[64][66];
  int t = threadIdx.x;
#pragma unroll
  for (int s = 0; s < 4; ++s) {
    int q = s * 256 + t;
    int r = q >> 4, c4 = q & 15;
    int j = j0 + r;
    float dv = d[b * NN + j];
    float4 v = *(const float4*)(X + ((size_t)(b * NN + j)) * NF + f0 + c4 * 4);
    T[r][c4 * 4 + 0] = f2bf(v.x * dv);
    T[r][c4 * 4 + 1] = f2bf(v.y * dv);
    T[r][c4 * 4 + 2] = f2bf(v.z * dv);
    T[r][c4 * 4 + 3] = f2bf(v.w * dv);
  }
  __syncthreads();
#pragma unroll
  for (int s = 0; s < 4; ++s) {
    int q = s * 256 + t;
    int fr = q >> 4, c4 = q & 15;
    ushort4 o;
    o.x = T[c4 * 4 + 0][fr]; o.y = T[c4 * 4 + 1][fr];
    o.z = T[c4 * 4 + 2][fr]; o.w = T[c4 * 4 + 3][fr];
    *(ushort4*)(XpT + ((size_t)(b * NF + f0 + fr)) * NN + j0 + c4 * 4) = o;
  }
}

// ---- Fused: H = d_i*(adjb@Xp + Xp_i) ; out = relu(H@W^T + bias) ------------
// BM=64, BN=256, BK=32, 512 thr (8 waves 2x4), grid 256 = 1 block/CU.
// A: 8KB granules (2 steps) mod-3; B: 16KB/step quad-buffered. glds staging,
// depth-2 prefetch, counted vmcnt(5), raw s_barrier. Swizzle via glds SOURCE.
#define BBASE 24576

#define FUSED_STEP(K, ARB, H, AW, BW, VMC, IA, IB)                             \
  {                                                                            \
    if (IA) gload_lds16(a_src + (size_t)((K) + 2) * 32,                        \
                        smem + (AW) * 8192 + aw_dst);                          \
    if (IB) {                                                                  \
      gload_lds16(b_src0 + (size_t)((K) + 2) * 32,                            \
                  smem + BBASE + (BW) * 16384 + bw_dst0);                      \
      gload_lds16(b_src1 + (size_t)((K) + 2) * 32,                            \
                  smem + BBASE + (BW) * 16384 + bw_dst1);                      \
    }                                                                          \
    __builtin_amdgcn_sched_barrier(0);                                         \
    asm volatile("s_waitcnt vmcnt(" VMC ")" ::: "memory");                     \
    __builtin_amdgcn_sched_barrier(0);                                         \
    __builtin_amdgcn_s_barrier();                                              \
    __builtin_amdgcn_sched_barrier(0);                                         \
    const char* Ab = smem + (ARB) * 8192 + ((H) << 12);                        \
    const char* Bb = smem + BBASE + ((K) & 3) * 16384;                         \
    bf16x8 af0 = *(const bf16x8*)(Ab + aoff0);                                 \
    bf16x8 af1 = *(const bf16x8*)(Ab + aoff0 + 1024);                          \
    bf16x8 b0 = *(const bf16x8*)(Bb + boff0);                                  \
    bf16x8 b1 = *(const bf16x8*)(Bb + boff0 + 1024);                           \
    bf16x8 b2 = *(const bf16x8*)(Bb + boff0 + 2048);                           \
    bf16x8 b3 = *(const bf16x8*)(Bb + boff0 + 3072);                           \
    asm volatile("s_waitcnt lgkmcnt(0)" ::: "memory");                         \
    __builtin_amdgcn_sched_barrier(0);                                         \
    __builtin_amdgcn_s_setprio(1);                                             \
    acc[0][0] = __builtin_amdgcn_mfma_f32_16x16x32_bf16(af0, b0, acc[0][0], 0, 0, 0); \
    acc[0][1] = __builtin_amdgcn_mfma_f32_16x16x32_bf16(af0, b1, acc[0][1], 0, 0, 0); \
    acc[0][2] = __builtin_amdgcn_mfma_f32_16x16x32_bf16(af0, b2, acc[0][2], 0, 0, 0); \
    acc[0][3] = __builtin_amdgcn_mfma_f32_16x16x32_bf16(af0, b3, acc[0][3], 0, 0, 0); \
    acc[1][0] = __builtin_amdgcn_mfma_f32_16x16x32_bf16(af1, b0, acc[1][0], 0, 0, 0); \
    acc[1][1] = __builtin_amdgcn_mfma_f32_16x16x32_bf16(af1, b1, acc[1][1], 0, 0, 0); \
    acc[1][2] = __builtin_amdgcn_mfma_f32_16x16x32_bf16(af1, b2, acc[1][2], 0, 0, 0); \
    acc[1][3] = __builtin_amdgcn_mfma_f32_16x16x32_bf16(af1, b3, acc[1][3], 0, 0, 0); \
    __builtin_amdgcn_s_setprio(0);                                             \
    __builtin_amdgcn_sched_barrier(0);                                         \
  }

__global__ __launch_bounds__(512, 2) void k_fused(
    const u16* __restrict__ adjb, const u16* __restrict__ XpT,
    const float* __restrict__ dsc, const u16* __restrict__ Wb,
    const float* __restrict__ bias, float* __restrict__ out) {
  int flat = blockIdx.x;
  int b = flat & 7, mt = flat >> 3;  // batch->XCD affinity
  int i0 = mt * 64;

  __shared__ __align__(16) char smem[90112];  // A 3x8K | B 4x16K ; Hs aliases
  u16* Hs = (u16*)smem;                       // 64 x 264 u16 = 33.8 KB

  int t = threadIdx.x;
  int lane = t & 63, w = t >> 6;
  int l15 = lane & 15, l4 = lane >> 4;
  int wr = w >> 2, wc = w & 3;

  const u16* adjbb = adjb + ((size_t)b * NN + i0) * NN;
  const u16* XpTb = XpT + (size_t)b * NF * NN;

  // A staging: slot s = w*64+lane over 8KB granule (2 step-tiles of [64][32])
  int sA = (w << 6) + lane;
  int uA = sA >> 8;            // which step within granule (wave-uniform)
  int rA = (sA >> 2) & 63;
  int cA = sA & 3;
  const u16* a_src = adjbb + (size_t)rA * NN + uA * 32 +
                     ((cA ^ ((rA >> 1) & 3)) << 3);
  int aw_dst = w << 10;

  // B staging: 1024 slots of [256][32]; thread handles slots t and 512+t
  int n0s = sA >> 2, c0s = sA & 3;
  const u16* b_src0 = XpTb + (size_t)n0s * NN + ((c0s ^ ((n0s >> 1) & 3)) << 3);
  int s1 = 512 + sA;
  int n1s = s1 >> 2, c1s = s1 & 3;
  const u16* b_src1 = XpTb + (size_t)n1s * NN + ((c1s ^ ((n1s >> 1) & 3)) << 3);
  int bw_dst0 = w << 10;
  int bw_dst1 = 8192 + (w << 10);

  // frag read offsets (16B chunk swizzle c ^ ((row>>1)&3))
  int swz = (l4 ^ ((l15 >> 1) & 3)) << 4;
  int aoff0 = (wr * 32 + l15) * 64 + swz;
  int boff0 = (wc * 64 + l15) * 64 + swz;

  f32x4 acc[2][4] = {};

  // ---- prologue: A granule0 -> Abuf0; B(0)->Bbuf0; B(1)->Bbuf1 ----
  gload_lds16(a_src, smem + aw_dst);
  gload_lds16(b_src0, smem + BBASE + bw_dst0);
  gload_lds16(b_src1, smem + BBASE + bw_dst1);
  gload_lds16(b_src0 + 32, smem + BBASE + 16384 + bw_dst0);
  gload_lds16(b_src1 + 32, smem + BBASE + 16384 + bw_dst1);
  __builtin_amdgcn_sched_barrier(0);

  // ---- main loop: 12-step period (A granules mod 3, B bufs mod 4) ----
  for (int kb = 0; kb < 60; kb += 12) {
    FUSED_STEP(kb + 0, 0, 0, 1, 2, "5", 1, 1)
    FUSED_STEP(kb + 1, 0, 1, 0, 3, "5", 0, 1)
    FUSED_STEP(kb + 2, 1, 0, 2, 0, "5", 1, 1)
    FUSED_STEP(kb + 3, 1, 1, 0, 1, "5", 0, 1)
    FUSED_STEP(kb + 4, 2, 0, 0, 2, "5", 1, 1)
    FUSED_STEP(kb + 5, 2, 1, 0, 3, "5", 0, 1)
    FUSED_STEP(kb + 6, 0, 0, 1, 0, "5", 1, 1)
    FUSED_STEP(kb + 7, 0, 1, 0, 1, "5", 0, 1)
    FUSED_STEP(kb + 8, 1, 0, 2, 2, "5", 1, 1)
    FUSED_STEP(kb + 9, 1, 1, 0, 3, "5", 0, 1)
    FUSED_STEP(kb + 10, 2, 0, 0, 0, "5", 1, 1)
    FUSED_STEP(kb + 11, 2, 1, 0, 1, "5", 0, 1)
  }
  // ---- tail: steps 60..63 ----
  FUSED_STEP(60, 0, 0, 1, 2, "5", 1, 1)
  FUSED_STEP(61, 0, 1, 0, 3, "5", 0, 1)
  FUSED_STEP(62, 1, 0, 0, 0, "2", 0, 0)
  FUSED_STEP(63, 1, 1, 0, 0, "0", 0, 0)

  __syncthreads();  // all frag reads done before Hs aliases staging buffers

  // ---- epilogue 1: H tile -> LDS bf16 [64][264]; +I term from XpT (L2) ----
  const float* db = dsc + b * NN;
#pragma unroll
  for (int mi = 0; mi < 2; ++mi) {
#pragma unroll
    for (int ni = 0; ni < 4; ++ni) {
      int f = wc * 64 + ni * 16 + l15;
      ushort4 xv = *(const ushort4*)(XpTb + (size_t)f * NN + i0 +
                                     wr * 32 + mi * 16 + l4 * 4);
#pragma unroll
      for (int qq = 0; qq < 4; ++qq) {
        int il = wr * 32 + mi * 16 + l4 * 4 + qq;
        float dv = db[i0 + il];
        float xpv = bf2f(((const u16*)&xv)[qq]);
        float hv = dv * (acc[mi][ni][qq] + xpv);
        Hs[il * 264 + f] = f2bf(hv);
      }
    }
  }
  __syncthreads();

  // ---- epilogue 2: out = relu(H @ W^T + bias), W frags from L2 ----
  f32x4 acc2[2][4] = {};
#pragma unroll
  for (int kk = 0; kk < 256; kk += 32) {
    bf16x8 a2[2], b2[4];
#pragma unroll
    for (int mi = 0; mi < 2; ++mi) {
      int r = wr * 32 + mi * 16 + l15;
      a2[mi] = *(const bf16x8*)&Hs[r * 264 + kk + l4 * 8];
    }
#pragma unroll
    for (int ni = 0; ni < 4; ++ni) {
      int o = wc * 64 + ni * 16 + l15;
      b2[ni] = *(const bf16x8*)&Wb[(size_t)o * 256 + kk + l4 * 8];
    }
#pragma unroll
    for (int mi = 0; mi < 2; ++mi)
#pragma unroll
      for (int ni = 0; ni < 4; ++ni)
        acc2[mi][ni] = __builtin_amdgcn_mfma_f32_16x16x32_bf16(a2[mi], b2[ni],
                                                               acc2[mi][ni], 0, 0, 0);
  }

  float* outb = out + ((size_t)b * NN + i0) * NF;
#pragma unroll
  for (int mi = 0; mi < 2; ++mi) {
#pragma unroll
    for (int qq = 0; qq < 4; ++qq) {
      int il = wr * 32 + mi * 16 + l4 * 4 + qq;
#pragma unroll
      for (int ni = 0; ni < 4; ++ni) {
        int o = wc * 64 + ni * 16 + l15;
        float v = acc2[mi][ni][qq] + bias[o];
        outb[(size_t)il * NF + o] = fmaxf(v, 0.f);
      }
    }
  }
}

extern "C" void kernel_launch(void* const* d_in, const int* in_sizes, int n_in,
                              void* d_out, int out_size, void* d_ws, size_t ws_size,
                              hipStream_t stream) {
  const float* X    = (const float*)d_in[0];
  const float* adj  = (const float*)d_in[1];
  const float* W    = (const float*)d_in[2];
  const float* bias = (const float*)d_in[3];
  float* out = (float*)d_out;

  char* ws = (char*)d_ws;
  float* dsc  = (float*)(ws);                          // 64 KB
  u16*   Wb   = (u16*)(ws + 65536);                    // 128 KB
  u16*   XpT  = (u16*)(ws + 262144);                   // 8 MB
  u16*   adjb = (u16*)(ws + 262144 + 8388608);         // 64 MB

  k_rowsum<<<dim3(16448), dim3(256), 0, stream>>>(adj, adjb, dsc, W, Wb);
  k_xprep<<<dim3(32, 4, 8), dim3(256), 0, stream>>>(X, dsc, XpT);
  k_fused<<<dim3(256), dim3(512), 0, stream>>>(adjb, XpT, dsc, Wb, bias, out);
}

// Round 9
// 73.142 us; speedup vs baseline: 1.5452x; 1.0347x over previous
//
#include <hip/hip_runtime.h>
#include <stdint.h>

typedef __attribute__((ext_vector_type(8))) short bf16x8;
typedef __attribute__((ext_vector_type(8))) unsigned short u16x8;
typedef __attribute__((ext_vector_type(4))) float f32x4;
typedef unsigned short u16;

constexpr int NN = 2048, NF = 256;

__device__ inline u16 f2bf(float f) {
  uint32_t u = __builtin_bit_cast(uint32_t, f);
  uint32_t r = (u + 0x7FFFu + ((u >> 16) & 1u)) >> 16;
  return (u16)r;
}
__device__ inline float bf2f(u16 h) {
  uint32_t u = ((uint32_t)h) << 16;
  return __builtin_bit_cast(float, u);
}

__device__ inline void gload_lds16(const void* g, void* l) {
  __builtin_amdgcn_global_load_lds(
      (const __attribute__((address_space(1))) uint32_t*)g,
      (__attribute__((address_space(3))) uint32_t*)l,
      16, 0, 0);
}

// ---- K1: d[row]=rsqrt(1+sum adj[row,:]); tail blocks: Wconv ----------------
__global__ __launch_bounds__(256) void k_rowsum(const float* __restrict__ adj,
                                                float* __restrict__ d,
                                                const float* __restrict__ W,
                                                u16* __restrict__ Wb) {
  if (blockIdx.x >= 16384) {  // W fp32 -> bf16 (64 blocks)
    int i = (blockIdx.x - 16384) * 256 + threadIdx.x;
    float4 v = ((const float4*)W)[i];
    ushort4 o;
    o.x = f2bf(v.x); o.y = f2bf(v.y); o.z = f2bf(v.z); o.w = f2bf(v.w);
    *(ushort4*)(Wb + (size_t)i * 4) = o;
    return;
  }
  int row = blockIdx.x;
  const float4* p = (const float4*)(adj + (size_t)row * NN);
  float s = 0.f;
#pragma unroll
  for (int c = 0; c < 2; ++c) {
    float4 v = p[threadIdx.x + 256 * c];
    s += v.x + v.y + v.z + v.w;
  }
#pragma unroll
  for (int off = 32; off > 0; off >>= 1) s += __shfl_down(s, off, 64);
  __shared__ float red[4];
  int lane = threadIdx.x & 63, w = threadIdx.x >> 6;
  if (lane == 0) red[w] = s;
  __syncthreads();
  if (threadIdx.x == 0) {
    float t = red[0] + red[1] + red[2] + red[3] + 1.0f;
    d[row] = 1.0f / sqrtf(t);
  }
}

// ---- K2: XpT[b,f,j] = bf16(d_j * X[b,j,f])  (plain transpose) --------------
__global__ __launch_bounds__(256) void k_xprep(const float* __restrict__ X,
                                               const float* __restrict__ d,
                                               u16* __restrict__ XpT) {
  int jt = blockIdx.x, ft = blockIdx.y, b = blockIdx.z;
  int j0 = jt * 64, f0 = ft * 64;
  __shared__ u16 T[64][66];
  int t = threadIdx.x;
#pragma unroll
  for (int s = 0; s < 4; ++s) {
    int q = s * 256 + t;
    int r = q >> 4, c4 = q & 15;
    int j = j0 + r;
    float dv = d[b * NN + j];
    float4 v = *(const float4*)(X + ((size_t)(b * NN + j)) * NF + f0 + c4 * 4);
    T[r][c4 * 4 + 0] = f2bf(v.x * dv);
    T[r][c4 * 4 + 1] = f2bf(v.y * dv);
    T[r][c4 * 4 + 2] = f2bf(v.z * dv);
    T[r][c4 * 4 + 3] = f2bf(v.w * dv);
  }
  __syncthreads();
#pragma unroll
  for (int s = 0; s < 4; ++s) {
    int q = s * 256 + t;
    int fr = q >> 4, c4 = q & 15;
    ushort4 o;
    o.x = T[c4 * 4 + 0][fr]; o.y = T[c4 * 4 + 1][fr];
    o.z = T[c4 * 4 + 2][fr]; o.w = T[c4 * 4 + 3][fr];
    *(ushort4*)(XpT + ((size_t)(b * NF + f0 + fr)) * NN + j0 + c4 * 4) = o;
  }
}

// ---- Fused: H = d_i*(adj@Xp + Xp_i) ; out = relu(H@W^T + bias) -------------
// BM=64, BN=256, BK=32, 512 thr (8 waves 2x4), grid 256 = 1 block/CU.
// Round-7 step schedule (1 barrier/step, writes 2 barriers ahead of reads).
// A: fp32 adj (L3) -> regs (3 sets, mod-3) -> cvt -> ds_write, granules mod-3.
// B: glds 2/step, quad-buffered. Counted vmcnt (issue order [B,B,A,A]).
#define BBASE 24576

#define MFMA8(AB, BB)                                                          \
  {                                                                            \
    bf16x8 af0 = *(const bf16x8*)((AB) + aoff0);                               \
    bf16x8 af1 = *(const bf16x8*)((AB) + aoff0 + 1024);                        \
    bf16x8 b0 = *(const bf16x8*)((BB) + boff0);                                \
    bf16x8 b1 = *(const bf16x8*)((BB) + boff0 + 1024);                         \
    bf16x8 b2 = *(const bf16x8*)((BB) + boff0 + 2048);                         \
    bf16x8 b3 = *(const bf16x8*)((BB) + boff0 + 3072);                         \
    asm volatile("s_waitcnt lgkmcnt(0)" ::: "memory");                         \
    __builtin_amdgcn_sched_barrier(0);                                         \
    __builtin_amdgcn_s_setprio(1);                                             \
    acc[0][0] = __builtin_amdgcn_mfma_f32_16x16x32_bf16(af0, b0, acc[0][0], 0, 0, 0); \
    acc[0][1] = __builtin_amdgcn_mfma_f32_16x16x32_bf16(af0, b1, acc[0][1], 0, 0, 0); \
    acc[0][2] = __builtin_amdgcn_mfma_f32_16x16x32_bf16(af0, b2, acc[0][2], 0, 0, 0); \
    acc[0][3] = __builtin_amdgcn_mfma_f32_16x16x32_bf16(af0, b3, acc[0][3], 0, 0, 0); \
    acc[1][0] = __builtin_amdgcn_mfma_f32_16x16x32_bf16(af1, b0, acc[1][0], 0, 0, 0); \
    acc[1][1] = __builtin_amdgcn_mfma_f32_16x16x32_bf16(af1, b1, acc[1][1], 0, 0, 0); \
    acc[1][2] = __builtin_amdgcn_mfma_f32_16x16x32_bf16(af1, b2, acc[1][2], 0, 0, 0); \
    acc[1][3] = __builtin_amdgcn_mfma_f32_16x16x32_bf16(af1, b3, acc[1][3], 0, 0, 0); \
    __builtin_amdgcn_s_setprio(0);                                             \
  }

// One PAIR = steps 2G (even) + 2G+1 (odd).
// RG: A granule read (lit). WG: granule written (even step). SN: reg set
// loaded (pair G+4 data). SW: reg set written out (pair G+2 data).
// BR0/BR1: B bufs read. BW0/BW1: B bufs written (steps 2G+2 / 2G+3).
#define PAIR(G, RG, WG, SN, SW, BR0, BR1, BW0, BW1, VMC0, VMC1, IA, WA, IB0, IB1) \
  {                                                                            \
    /* ---- even step K=2G ---- */                                             \
    if (IB0) {                                                                 \
      gload_lds16(b_src0 + (size_t)(2 * (G) + 2) * 32,                         \
                  smem + BBASE + (BW0) * 16384 + bw0);                         \
      gload_lds16(b_src1 + (size_t)(2 * (G) + 2) * 32,                         \
                  smem + BBASE + (BW0) * 16384 + bw1);                         \
    }                                                                          \
    if (IA) {                                                                  \
      aN0[SN] = *(const float4*)(a_gsrc + (size_t)((G) + 4) * 64);             \
      aN1[SN] = *(const float4*)(a_gsrc + (size_t)((G) + 4) * 64 + 4);         \
    }                                                                          \
    __builtin_amdgcn_sched_barrier(0);                                         \
    asm volatile("s_waitcnt vmcnt(" VMC0 ") lgkmcnt(0)" ::: "memory");         \
    __builtin_amdgcn_sched_barrier(0);                                         \
    __builtin_amdgcn_s_barrier();                                              \
    __builtin_amdgcn_sched_barrier(0);                                         \
    MFMA8(smem + (RG) * 8192, smem + BBASE + (BR0) * 16384)                    \
    __builtin_amdgcn_sched_barrier(0);                                         \
    if (WA) {                                                                  \
      float4 c0 = aN0[SW], c1 = aN1[SW];                                       \
      u16x8 pk;                                                                \
      pk[0] = f2bf(c0.x); pk[1] = f2bf(c0.y); pk[2] = f2bf(c0.z);              \
      pk[3] = f2bf(c0.w); pk[4] = f2bf(c1.x); pk[5] = f2bf(c1.y);              \
      pk[6] = f2bf(c1.z); pk[7] = f2bf(c1.w);                                  \
      *(u16x8*)(smem + (WG) * 8192 + a_ldst) = pk;                             \
    }                                                                          \
    __builtin_amdgcn_sched_barrier(0);                                         \
    /* ---- odd step K=2G+1 ---- */                                            \
    if (IB1) {                                                                 \
      gload_lds16(b_src0 + (size_t)(2 * (G) + 3) * 32,                         \
                  smem + BBASE + (BW1) * 16384 + bw0);                         \
      gload_lds16(b_src1 + (size_t)(2 * (G) + 3) * 32,                         \
                  smem + BBASE + (BW1) * 16384 + bw1);                         \
    }                                                                          \
    __builtin_amdgcn_sched_barrier(0);                                         \
    asm volatile("s_waitcnt vmcnt(" VMC1 ") lgkmcnt(0)" ::: "memory");         \
    __builtin_amdgcn_sched_barrier(0);                                         \
    __builtin_amdgcn_s_barrier();                                              \
    __builtin_amdgcn_sched_barrier(0);                                         \
    MFMA8(smem + (RG) * 8192 + 4096, smem + BBASE + (BR1) * 16384)             \
    __builtin_amdgcn_sched_barrier(0);                                         \
  }

__global__ __launch_bounds__(512, 2) void k_fused(
    const float* __restrict__ adj, const u16* __restrict__ XpT,
    const float* __restrict__ dsc, const u16* __restrict__ Wb,
    const float* __restrict__ bias, float* __restrict__ out) {
  int flat = blockIdx.x;
  int b = flat & 7, mt = flat >> 3;  // batch->XCD affinity
  int i0 = mt * 64;

  __shared__ __align__(16) char smem[90112];  // A 3x8K | B 4x16K ; Hs aliases
  u16* Hs = (u16*)smem;                       // 64 x 264 u16 = 33.8 KB

  int t = threadIdx.x;
  int lane = t & 63, w = t >> 6;
  int l15 = lane & 15, l4 = lane >> 4;
  int wr = w >> 2, wc = w & 3;

  const float* adjf = adj + ((size_t)b * NN + i0) * NN;
  const u16* XpTb = XpT + (size_t)b * NF * NN;

  // A staging: thread t -> row rA=t>>3, 8-float chunk kc=t&7 within a pair
  // (pair P = 64 k-cols). LDS granule: [2 halves 4KB][64 rows x 4 chunks swz].
  int rA = t >> 3, kc = t & 7;
  const float* a_gsrc = adjf + (size_t)rA * NN + kc * 8;
  int a_ldst = (kc >> 2) * 4096 + rA * 64 + (((kc & 3) ^ ((rA >> 1) & 3)) << 4);

  // B staging (glds, source-swizzled): slots t and t+512 of [256][32]
  int n0s = t >> 2, c0s = t & 3;
  const u16* b_src0 = XpTb + (size_t)n0s * NN + ((c0s ^ ((n0s >> 1) & 3)) << 3);
  int s1 = 512 + t;
  int n1s = s1 >> 2, c1s = s1 & 3;
  const u16* b_src1 = XpTb + (size_t)n1s * NN + ((c1s ^ ((n1s >> 1) & 3)) << 3);
  int bw0 = w << 10;
  int bw1 = 8192 + (w << 10);

  // frag read byte offsets
  int swz = (l4 ^ ((l15 >> 1) & 3)) << 4;
  int aoff0 = wr * 2048 + l15 * 64 + swz;
  int boff0 = (wc * 64 + l15) * 64 + swz;

  f32x4 acc[2][4] = {};
  float4 aN0[3], aN1[3];

  // ---- prologue ----
  {
    float4 p0a = *(const float4*)(a_gsrc);            // pair 0
    float4 p0b = *(const float4*)(a_gsrc + 4);
    float4 p1a = *(const float4*)(a_gsrc + 64);       // pair 1
    float4 p1b = *(const float4*)(a_gsrc + 68);
    __builtin_amdgcn_sched_barrier(0);
    gload_lds16(b_src0, smem + BBASE + bw0);          // B(0) -> buf0
    gload_lds16(b_src1, smem + BBASE + bw1);
    gload_lds16(b_src0 + 32, smem + BBASE + 16384 + bw0);  // B(1) -> buf1
    gload_lds16(b_src1 + 32, smem + BBASE + 16384 + bw1);
    __builtin_amdgcn_sched_barrier(0);
    aN0[1] = *(const float4*)(a_gsrc + 128);          // pair 2 -> set 1
    aN1[1] = *(const float4*)(a_gsrc + 132);
    aN0[2] = *(const float4*)(a_gsrc + 192);          // pair 3 -> set 2
    aN1[2] = *(const float4*)(a_gsrc + 196);
    __builtin_amdgcn_sched_barrier(0);
    u16x8 pk;
    pk[0] = f2bf(p0a.x); pk[1] = f2bf(p0a.y); pk[2] = f2bf(p0a.z);
    pk[3] = f2bf(p0a.w); pk[4] = f2bf(p0b.x); pk[5] = f2bf(p0b.y);
    pk[6] = f2bf(p0b.z); pk[7] = f2bf(p0b.w);
    *(u16x8*)(smem + a_ldst) = pk;                    // granule 0
    pk[0] = f2bf(p1a.x); pk[1] = f2bf(p1a.y); pk[2] = f2bf(p1a.z);
    pk[3] = f2bf(p1a.w); pk[4] = f2bf(p1b.x); pk[5] = f2bf(p1b.y);
    pk[6] = f2bf(p1b.z); pk[7] = f2bf(p1b.w);
    *(u16x8*)(smem + 8192 + a_ldst) = pk;             // granule 1
    __builtin_amdgcn_sched_barrier(0);
  }

  // ---- main loop: pairs 0..23 (period 6) ----
  for (int gb = 0; gb < 24; gb += 6) {
    PAIR(gb + 0, 0, 2, 0, 1, 0, 1, 2, 3, "8", "6", 1, 1, 1, 1)
    PAIR(gb + 1, 1, 0, 1, 2, 2, 3, 0, 1, "8", "6", 1, 1, 1, 1)
    PAIR(gb + 2, 2, 1, 2, 0, 0, 1, 2, 3, "8", "6", 1, 1, 1, 1)
    PAIR(gb + 3, 0, 2, 0, 1, 2, 3, 0, 1, "8", "6", 1, 1, 1, 1)
    PAIR(gb + 4, 1, 0, 1, 2, 0, 1, 2, 3, "8", "6", 1, 1, 1, 1)
    PAIR(gb + 5, 2, 1, 2, 0, 2, 3, 0, 1, "8", "6", 1, 1, 1, 1)
  }
  // ---- tail: pairs 24..31 ----
  PAIR(24, 0, 2, 0, 1, 0, 1, 2, 3, "8", "6", 1, 1, 1, 1)
  PAIR(25, 1, 0, 1, 2, 2, 3, 0, 1, "8", "6", 1, 1, 1, 1)
  PAIR(26, 2, 1, 2, 0, 0, 1, 2, 3, "8", "6", 1, 1, 1, 1)
  PAIR(27, 0, 2, 0, 1, 2, 3, 0, 1, "8", "6", 1, 1, 1, 1)
  PAIR(28, 1, 0, 1, 2, 0, 1, 2, 3, "6", "4", 0, 1, 1, 1)
  PAIR(29, 2, 1, 2, 0, 2, 3, 0, 1, "4", "4", 0, 1, 1, 1)
  PAIR(30, 0, 2, 0, 1, 0, 1, 2, 3, "4", "4", 0, 0, 1, 1)
  PAIR(31, 1, 0, 1, 2, 2, 3, 0, 1, "2", "0", 0, 0, 0, 0)

  __syncthreads();  // all staging/frag traffic done before Hs aliases smem

  // ---- epilogue 1: H tile -> LDS bf16 [64][264]; +I term from XpT (L2) ----
  const float* db = dsc + b * NN;
#pragma unroll
  for (int mi = 0; mi < 2; ++mi) {
#pragma unroll
    for (int ni = 0; ni < 4; ++ni) {
      int f = wc * 64 + ni * 16 + l15;
      ushort4 xv = *(const ushort4*)(XpTb + (size_t)f * NN + i0 +
                                     wr * 32 + mi * 16 + l4 * 4);
#pragma unroll
      for (int qq = 0; qq < 4; ++qq) {
        int il = wr * 32 + mi * 16 + l4 * 4 + qq;
        float dv = db[i0 + il];
        float xpv = bf2f(((const u16*)&xv)[qq]);
        float hv = dv * (acc[mi][ni][qq] + xpv);
        Hs[il * 264 + f] = f2bf(hv);
      }
    }
  }
  __syncthreads();

  // ---- epilogue 2: out = relu(H @ W^T + bias), W frags from L2 ----
  f32x4 acc2[2][4] = {};
#pragma unroll
  for (int kk = 0; kk < 256; kk += 32) {
    bf16x8 a2[2], b2[4];
#pragma unroll
    for (int mi = 0; mi < 2; ++mi) {
      int r = wr * 32 + mi * 16 + l15;
      a2[mi] = *(const bf16x8*)&Hs[r * 264 + kk + l4 * 8];
    }
#pragma unroll
    for (int ni = 0; ni < 4; ++ni) {
      int o = wc * 64 + ni * 16 + l15;
      b2[ni] = *(const bf16x8*)&Wb[(size_t)o * 256 + kk + l4 * 8];
    }
#pragma unroll
    for (int mi = 0; mi < 2; ++mi)
#pragma unroll
      for (int ni = 0; ni < 4; ++ni)
        acc2[mi][ni] = __builtin_amdgcn_mfma_f32_16x16x32_bf16(a2[mi], b2[ni],
                                                               acc2[mi][ni], 0, 0, 0);
  }

  float* outb = out + ((size_t)b * NN + i0) * NF;
#pragma unroll
  for (int mi = 0; mi < 2; ++mi) {
#pragma unroll
    for (int qq = 0; qq < 4; ++qq) {
      int il = wr * 32 + mi * 16 + l4 * 4 + qq;
#pragma unroll
      for (int ni = 0; ni < 4; ++ni) {
        int o = wc * 64 + ni * 16 + l15;
        float v = acc2[mi][ni][qq] + bias[o];
        outb[(size_t)il * NF + o] = fmaxf(v, 0.f);
      }
    }
  }
}

extern "C" void kernel_launch(void* const* d_in, const int* in_sizes, int n_in,
                              void* d_out, int out_size, void* d_ws, size_t ws_size,
                              hipStream_t stream) {
  const float* X    = (const float*)d_in[0];
  const float* adj  = (const float*)d_in[1];
  const float* W    = (const float*)d_in[2];
  const float* bias = (const float*)d_in[3];
  float* out = (float*)d_out;

  char* ws = (char*)d_ws;
  float* dsc = (float*)(ws);                 // 64 KB
  u16*   Wb  = (u16*)(ws + 65536);           // 128 KB
  u16*   XpT = (u16*)(ws + 262144);          // 8 MB

  k_rowsum<<<dim3(16448), dim3(256), 0, stream>>>(adj, dsc, W, Wb);
  k_xprep<<<dim3(32, 4, 8), dim3(256), 0, stream>>>(X, dsc, XpT);
  k_fused<<<dim3(256), dim3(512), 0, stream>>>(adj, XpT, dsc, Wb, bias, out);
}